// Round 1
// baseline (198.299 us; speedup 1.0000x reference)
//
#include <hip/hip_runtime.h>

#define N_NODES 100000
#define N_EDGES 1600000
#define EPS 1e-5f

typedef __bf16    bf16x8 __attribute__((ext_vector_type(8)));
typedef _Float16  f16x8  __attribute__((ext_vector_type(8)));
typedef float     f32x4  __attribute__((ext_vector_type(4)));

// ---------------------------------------------------------------------------
// Kernel 0: per-node GEMM  g[v] = W_f . feat[v] + W_n . node[v]   (f16 out)
// One wave per 16 nodes. A rows = contiguous nodes (f32 -> bf16 inline),
// B = W rows (f32 -> bf16 inline, hot in L1). 12 MFMAs per wave.
// MFMA 16x16x32 bf16 layouts (HW-verified, mirrors previous passing kernel):
//   A[m=lane&15][k=quad*8+j], B[k=quad*8+j][n=lane&15],
//   D: col n = lane&15, row m = quad*4+reg
// ---------------------------------------------------------------------------
__global__ __launch_bounds__(256) void gemm_kernel(
    const float* __restrict__ nodep, const float* __restrict__ feat,
    const float* __restrict__ W, unsigned short* __restrict__ g) {
  const int lane = threadIdx.x & 63;
  const int wave = (int)((blockIdx.x * blockDim.x + threadIdx.x) >> 6);
  const int c    = lane & 15;
  const int quad = lane >> 4;
  if (wave >= N_NODES / 16) return;   // 6250 groups

  // B fragments: W row n = t*16+c, k = s*32 + quad*8 + j (pad k>=67 with 0)
  bf16x8 Bfrag[4][3];
#pragma unroll
  for (int t = 0; t < 4; ++t) {
    const float* wrow = W + (t * 16 + c) * 67;
#pragma unroll
    for (int s = 0; s < 3; ++s) {
#pragma unroll
      for (int j = 0; j < 8; ++j) {
        int k = s * 32 + quad * 8 + j;
        Bfrag[t][s][j] = (k < 67) ? (__bf16)wrow[k] : (__bf16)0.0f;
      }
    }
  }

  // A fragments: node v = wave*16 + c supplies row m=c
  const int v = wave * 16 + c;
  const float* frow = feat + (size_t)v * 64 + quad * 8;
  bf16x8 A0, A1;
#pragma unroll
  for (int j = 0; j < 8; ++j) {
    A0[j] = (__bf16)frow[j];
    A1[j] = (__bf16)frow[32 + j];
  }
  bf16x8 A2;
#pragma unroll
  for (int j = 0; j < 8; ++j) A2[j] = (__bf16)0.0f;
  if (quad == 0) {
    const float* np = nodep + (size_t)v * 3;
    A2[0] = (__bf16)np[0];
    A2[1] = (__bf16)np[1];
    A2[2] = (__bf16)np[2];
  }

#pragma unroll
  for (int t = 0; t < 4; ++t) {
    f32x4 acc = {0.f, 0.f, 0.f, 0.f};
    acc = __builtin_amdgcn_mfma_f32_16x16x32_bf16(A0, Bfrag[t][0], acc, 0, 0, 0);
    acc = __builtin_amdgcn_mfma_f32_16x16x32_bf16(A1, Bfrag[t][1], acc, 0, 0, 0);
    acc = __builtin_amdgcn_mfma_f32_16x16x32_bf16(A2, Bfrag[t][2], acc, 0, 0, 0);
    // store: node = wave*16 + quad*4 + r, dim = t*16 + c  (f16, RTN)
    unsigned short* gp = g + (size_t)(wave * 16 + quad * 4) * 64 + t * 16 + c;
#pragma unroll
    for (int r = 0; r < 4; ++r)
      gp[r * 64] = __builtin_bit_cast(unsigned short, (_Float16)acc[r]);
  }
}

// ---------------------------------------------------------------------------
// Kernel 1: gather-reduce. One wave per node (grid-stride).
// h_e[d] = g[dst_e][d] - c_i[d],  c_i = W_n . node[i]  (constant over the
// node's 16 edges). Lane (ch=lane&7, r0=lane>>3) loads rows r0 and r0+8,
// cols ch*8..ch*8+7 (16B f16x8 each). Cross-lane reduce over lane bits 3..5.
// Outputs: per-node col max/min (f32) + per-wave col sum/sumsq partials.
// ---------------------------------------------------------------------------
__global__ __launch_bounds__(256) void gather_kernel(
    const float* __restrict__ nodep, const int* __restrict__ edges,
    const _Float16* __restrict__ g, const float* __restrict__ W,
    float* __restrict__ maxv, float* __restrict__ minv,
    float* __restrict__ stats, int nwaves) {
  const int lane = threadIdx.x & 63;
  const int wave = (int)((blockIdx.x * blockDim.x + threadIdx.x) >> 6);
  const int ch = lane & 7;    // col chunk: cols ch*8 .. ch*8+7
  const int r0 = lane >> 3;   // rows r0 and r0+8

  // W_n for this lane's 8 cols (hot, once per wave)
  float wn0[8], wn1[8], wn2[8];
#pragma unroll
  for (int j = 0; j < 8; ++j) {
    const float* wr = W + (ch * 8 + j) * 67 + 64;
    wn0[j] = wr[0]; wn1[j] = wr[1]; wn2[j] = wr[2];
  }

  float sh[8], sq[8];
#pragma unroll
  for (int j = 0; j < 8; ++j) { sh[j] = 0.f; sq[j] = 0.f; }

  int i = wave;
  int dst_own = 0;
  if (i < N_NODES && lane < 16) dst_own = edges[2 * (i + lane * N_NODES) + 1];

  for (; i < N_NODES; i += nwaves) {
    // prefetch next iteration's edge indices (independent of everything)
    const int inext = i + nwaves;
    int dst_nxt = 0;
    if (inext < N_NODES && lane < 16)
      dst_nxt = edges[2 * (inext + lane * N_NODES) + 1];

    const int dA = __shfl(dst_own, r0, 64);
    const int dB = __shfl(dst_own, r0 + 8, 64);
    f16x8 va = *(const f16x8*)(g + (size_t)dA * 64 + ch * 8);
    f16x8 vb = *(const f16x8*)(g + (size_t)dB * 64 + ch * 8);

    // c for this node's cols (scalar loads: i is wave-uniform); overlaps gather
    const float nx = nodep[3 * i], ny = nodep[3 * i + 1], nz = nodep[3 * i + 2];

    float mx[8], mn[8];
#pragma unroll
    for (int j = 0; j < 8; ++j) {
      float cj = fmaf(wn2[j], nz, fmaf(wn1[j], ny, wn0[j] * nx));
      float ha = (float)va[j] - cj;
      float hb = (float)vb[j] - cj;
      mx[j] = fmaxf(ha, hb);
      mn[j] = fminf(ha, hb);
      sh[j] += ha + hb;
      sq[j] = fmaf(ha, ha, sq[j]);
      sq[j] = fmaf(hb, hb, sq[j]);
    }
#pragma unroll
    for (int j = 0; j < 8; ++j) {
      mx[j] = fmaxf(mx[j], __shfl_xor(mx[j], 8, 64));
      mx[j] = fmaxf(mx[j], __shfl_xor(mx[j], 16, 64));
      mx[j] = fmaxf(mx[j], __shfl_xor(mx[j], 32, 64));
      mn[j] = fminf(mn[j], __shfl_xor(mn[j], 8, 64));
      mn[j] = fminf(mn[j], __shfl_xor(mn[j], 16, 64));
      mn[j] = fminf(mn[j], __shfl_xor(mn[j], 32, 64));
    }
    if (lane < 8) {   // ch == lane here; 8 lanes write 256B contiguous
      f32x4 a = {mx[0], mx[1], mx[2], mx[3]};
      f32x4 b = {mx[4], mx[5], mx[6], mx[7]};
      *(f32x4*)(maxv + (size_t)i * 64 + ch * 8)     = a;
      *(f32x4*)(maxv + (size_t)i * 64 + ch * 8 + 4) = b;
      f32x4 p = {mn[0], mn[1], mn[2], mn[3]};
      f32x4 q = {mn[4], mn[5], mn[6], mn[7]};
      *(f32x4*)(minv + (size_t)i * 64 + ch * 8)     = p;
      *(f32x4*)(minv + (size_t)i * 64 + ch * 8 + 4) = q;
    }
    dst_own = dst_nxt;
  }

  // finalize per-wave stats partials: sum across the 8 row-lanes per chunk
#pragma unroll
  for (int j = 0; j < 8; ++j) {
    sh[j] += __shfl_xor(sh[j], 8, 64);
    sh[j] += __shfl_xor(sh[j], 16, 64);
    sh[j] += __shfl_xor(sh[j], 32, 64);
    sq[j] += __shfl_xor(sq[j], 8, 64);
    sq[j] += __shfl_xor(sq[j], 16, 64);
    sq[j] += __shfl_xor(sq[j], 32, 64);
  }
  if (lane < 8) {
#pragma unroll
    for (int j = 0; j < 8; ++j) {
      stats[(size_t)(ch * 8 + j) * nwaves + wave]      = sh[j];   // sum
      stats[(size_t)(64 + ch * 8 + j) * nwaves + wave] = sq[j];   // sumsq
    }
  }
}

// ---------------------------------------------------------------------------
// Kernel 2: reduce per-wave partials -> scale/shift per output column.
// ---------------------------------------------------------------------------
__global__ __launch_bounds__(256) void stats_kernel(
    const float* __restrict__ stats, const float* __restrict__ gamma,
    const float* __restrict__ beta, float* __restrict__ ss, int nwaves) {
  int d = blockIdx.x;    // 0..63
  int t = threadIdx.x;
  const float* r1 = stats + (size_t)d * nwaves;
  const float* r2 = stats + (size_t)(64 + d) * nwaves;
  float a = 0.f, b = 0.f;
  for (int k = t; k < nwaves; k += 256) { a += r1[k]; b += r2[k]; }
  __shared__ float l1[256], l2[256];
  l1[t] = a; l2[t] = b;
  __syncthreads();
  for (int s = 128; s > 0; s >>= 1) {
    if (t < s) { l1[t] += l1[t + s]; l2[t] += l2[t + s]; }
    __syncthreads();
  }
  if (t == 0) {
    const float inv_ne = 1.0f / (float)N_EDGES;
    float mean = l1[0] * inv_ne;
    float var  = fmaxf(l2[0] * inv_ne - mean * mean, 0.f);
    float sc   = gamma[d] * rsqrtf(var + EPS);
    ss[d]      = sc;
    ss[64 + d] = beta[d] - mean * sc;
  }
}

// ---------------------------------------------------------------------------
// Kernel 3: out[i][d] = relu(sel * scale[d] + shift[d]), sel = max if scale>=0
// else min (relu(affine(.)) is monotone per column). In-place on d_out.
// ---------------------------------------------------------------------------
__global__ __launch_bounds__(256) void finalize_kernel(
    const float* __restrict__ minv, const float* __restrict__ ss,
    float* out) {
  int idx = blockIdx.x * 256 + threadIdx.x;   // < 6,400,000
  int d = idx & 63;
  float sc = ss[d], sh = ss[64 + d];
  float v = (sc >= 0.f) ? out[idx] : minv[idx];
  out[idx] = fmaxf(fmaf(v, sc, sh), 0.f);
}

// ---------------------------------------------------------------------------
extern "C" void kernel_launch(void* const* d_in, const int* in_sizes, int n_in,
                              void* d_out, int out_size, void* d_ws, size_t ws_size,
                              hipStream_t stream) {
  const float* nodep = (const float*)d_in[0];
  const float* feat  = (const float*)d_in[1];
  const float* W     = (const float*)d_in[2];
  const float* gamma = (const float*)d_in[3];
  const float* beta  = (const float*)d_in[4];
  const int*   edges = (const int*)d_in[5];

  // workspace layout (all 16B-aligned)
  char* ws = (char*)d_ws;
  unsigned short* g = (unsigned short*)ws;                    // 12,800,000 B
  float* minv  = (float*)(ws + 12800000);                     // 25,600,000 B
  float* stats = (float*)(ws + 12800000 + 25600000);          //  4,194,304 B
  float* ss    = (float*)(ws + 12800000 + 25600000 + 4194304);//       512 B
  float* maxv  = (float*)d_out;

  const int nwaves = 8192;   // 2048 blocks x 4 waves; ~12.2 nodes per wave

  gemm_kernel<<<1563, 256, 0, stream>>>(nodep, feat, W, g);
  gather_kernel<<<2048, 256, 0, stream>>>(nodep, edges, (const _Float16*)g, W,
                                          maxv, minv, stats, nwaves);
  stats_kernel<<<64, 256, 0, stream>>>(stats, gamma, beta, ss, nwaves);
  finalize_kernel<<<25000, 256, 0, stream>>>(minv, ss, maxv);
}

// Round 2
// 184.455 us; speedup vs baseline: 1.0751x; 1.0751x over previous
//
#include <hip/hip_runtime.h>

#define N_NODES 100000
#define N_EDGES 1600000
#define EPS 1e-5f

typedef __bf16    bf16x8 __attribute__((ext_vector_type(8)));
typedef _Float16  f16x2  __attribute__((ext_vector_type(2)));
typedef float     f32x4  __attribute__((ext_vector_type(4)));
typedef unsigned int u32;
typedef u32       u32x4  __attribute__((ext_vector_type(4)));

__device__ __forceinline__ u32 pkmax(u32 a, u32 b) {
  u32 d; asm("v_pk_max_f16 %0,%1,%2" : "=v"(d) : "v"(a), "v"(b)); return d;
}
__device__ __forceinline__ u32 pkmin(u32 a, u32 b) {
  u32 d; asm("v_pk_min_f16 %0,%1,%2" : "=v"(d) : "v"(a), "v"(b)); return d;
}
// c + lo(v) + hi(v)   (f16 halves, f32 accumulate)
__device__ __forceinline__ float halves_sum(u32 v, float c) {
  f16x2 p = __builtin_bit_cast(f16x2, v);
#if __has_builtin(__builtin_amdgcn_fdot2)
  f16x2 one2 = {(_Float16)1.0f, (_Float16)1.0f};
  return __builtin_amdgcn_fdot2(p, one2, c, false);
#else
  return c + (float)p[0] + (float)p[1];
#endif
}
// c + lo(v)^2 + hi(v)^2
__device__ __forceinline__ float halves_sq(u32 v, float c) {
  f16x2 p = __builtin_bit_cast(f16x2, v);
#if __has_builtin(__builtin_amdgcn_fdot2)
  return __builtin_amdgcn_fdot2(p, p, c, false);
#else
  float a = (float)p[0], b = (float)p[1];
  return fmaf(a, a, fmaf(b, b, c));
#endif
}

// ---------------------------------------------------------------------------
// Kernel 0: per-node GEMM  g[v] = W_f . feat[v] + W_n . node[v]   (f16 out)
// One wave per 16 nodes. 12 MFMAs per wave. (unchanged from prev round)
// ---------------------------------------------------------------------------
__global__ __launch_bounds__(256) void gemm_kernel(
    const float* __restrict__ nodep, const float* __restrict__ feat,
    const float* __restrict__ W, unsigned short* __restrict__ g) {
  const int lane = threadIdx.x & 63;
  const int wave = (int)((blockIdx.x * blockDim.x + threadIdx.x) >> 6);
  const int c    = lane & 15;
  const int quad = lane >> 4;
  if (wave >= N_NODES / 16) return;   // 6250 groups

  bf16x8 Bfrag[4][3];
#pragma unroll
  for (int t = 0; t < 4; ++t) {
    const float* wrow = W + (t * 16 + c) * 67;
#pragma unroll
    for (int s = 0; s < 3; ++s) {
#pragma unroll
      for (int j = 0; j < 8; ++j) {
        int k = s * 32 + quad * 8 + j;
        Bfrag[t][s][j] = (k < 67) ? (__bf16)wrow[k] : (__bf16)0.0f;
      }
    }
  }

  const int v = wave * 16 + c;
  const float* frow = feat + (size_t)v * 64 + quad * 8;
  bf16x8 A0, A1;
#pragma unroll
  for (int j = 0; j < 8; ++j) {
    A0[j] = (__bf16)frow[j];
    A1[j] = (__bf16)frow[32 + j];
  }
  bf16x8 A2;
#pragma unroll
  for (int j = 0; j < 8; ++j) A2[j] = (__bf16)0.0f;
  if (quad == 0) {
    const float* np = nodep + (size_t)v * 3;
    A2[0] = (__bf16)np[0];
    A2[1] = (__bf16)np[1];
    A2[2] = (__bf16)np[2];
  }

#pragma unroll
  for (int t = 0; t < 4; ++t) {
    f32x4 acc = {0.f, 0.f, 0.f, 0.f};
    acc = __builtin_amdgcn_mfma_f32_16x16x32_bf16(A0, Bfrag[t][0], acc, 0, 0, 0);
    acc = __builtin_amdgcn_mfma_f32_16x16x32_bf16(A1, Bfrag[t][1], acc, 0, 0, 0);
    acc = __builtin_amdgcn_mfma_f32_16x16x32_bf16(A2, Bfrag[t][2], acc, 0, 0, 0);
    unsigned short* gp = g + (size_t)(wave * 16 + quad * 4) * 64 + t * 16 + c;
#pragma unroll
    for (int r = 0; r < 4; ++r)
      gp[r * 64] = __builtin_bit_cast(unsigned short, (_Float16)acc[r]);
  }
}

// ---------------------------------------------------------------------------
// Kernel 1: gather-reduce with deferred c.
// Per node i: max/min/sum/sumsq of RAW g[dst] rows (16 edges x 64 cols).
//   max_e(g-c) = (max_e g) - c  -> c applied in finalize.
//   sum:   Sigma(g-c)  = Sigma g - 16*Sigma_i c_i           (c_i = Wn.n_i)
//   sumsq: Sigma(g-c)^2= Sigma g^2 - 2*Sigma_i c_i.S_i + 16*Sigma_i c_i^2
//     Sigma c_i   from node-coord sums L (3 scalars/wave),
//     Sigma c_i^2 from coord moments M (6 scalars/wave),
//     Sigma c_i.S_i from nS[d] = Sigma n_a,i * S_i[d] (3 accumulators/col).
// Lane (ch=lane&7, r0=lane>>3) handles rows r0,r0+8, cols ch*8..ch*8+7.
// Packed f16 max/min (v_pk_max_f16): 24 shuffles/node instead of 48.
// 2-deep index prefetch + 1-deep gather prefetch.
// ---------------------------------------------------------------------------
__global__ __launch_bounds__(256, 4) void gather_kernel(
    const float* __restrict__ nodep, const int* __restrict__ edges,
    const _Float16* __restrict__ g, const float* __restrict__ W,
    _Float16* __restrict__ gmax, _Float16* __restrict__ gmin,
    float* __restrict__ stats, int nwaves) {
  const int lane = threadIdx.x & 63;
  const int wave = (int)((blockIdx.x * blockDim.x + threadIdx.x) >> 6);
  const int ch = lane & 7;
  const int r0 = lane >> 3;

  float sh[8], sq[8], nxS[8], nyS[8], nzS[8];
#pragma unroll
  for (int j = 0; j < 8; ++j) {
    sh[j] = 0.f; sq[j] = 0.f; nxS[j] = 0.f; nyS[j] = 0.f; nzS[j] = 0.f;
  }
  float Lx = 0.f, Ly = 0.f, Lz = 0.f;
  float Mxx = 0.f, Myy = 0.f, Mzz = 0.f, Mxy = 0.f, Mxz = 0.f, Myz = 0.f;

  int iA = wave;
  int iN = iA + nwaves;
  // edge dst indices: lane<16 holds dst of edge k=lane (src = i + k*N)
  int dnxt = 0;
  u32x4 va = {0, 0, 0, 0}, vb = {0, 0, 0, 0};
  if (iA < N_NODES) {
    int dcur = 0;
    if (lane < 16) {
      dcur = edges[2 * (iA + lane * N_NODES) + 1];
      if (iN < N_NODES) dnxt = edges[2 * (iN + lane * N_NODES) + 1];
    }
    int dA = __shfl(dcur, r0, 64);
    int dB = __shfl(dcur, r0 + 8, 64);
    va = *(const u32x4*)(g + (size_t)dA * 64 + ch * 8);
    vb = *(const u32x4*)(g + (size_t)dB * 64 + ch * 8);
  }

#pragma unroll 1
  while (iA < N_NODES) {
    // --- issue next node's gathers (dnxt==0 for lanes>=16 / out of range) ---
    int dnA = __shfl(dnxt, r0, 64);
    int dnB = __shfl(dnxt, r0 + 8, 64);
    u32x4 vaN = *(const u32x4*)(g + (size_t)dnA * 64 + ch * 8);
    u32x4 vbN = *(const u32x4*)(g + (size_t)dnB * 64 + ch * 8);
    // --- prefetch edge indices two nodes ahead ---
    int i2 = iN + nwaves;
    int d2 = 0;
    if (lane < 16 && i2 < N_NODES) d2 = edges[2 * (i2 + lane * N_NODES) + 1];
    // --- node coords (wave-uniform) ---
    float nx = nodep[3 * iA], ny = nodep[3 * iA + 1], nz = nodep[3 * iA + 2];
    Lx += nx; Ly += ny; Lz += nz;
    Mxx = fmaf(nx, nx, Mxx); Myy = fmaf(ny, ny, Myy); Mzz = fmaf(nz, nz, Mzz);
    Mxy = fmaf(nx, ny, Mxy); Mxz = fmaf(nx, nz, Mxz); Myz = fmaf(ny, nz, Myz);

    // --- packed max/min over this lane's two rows ---
    u32 mx[4], mn[4];
#pragma unroll
    for (int q = 0; q < 4; ++q) {
      mx[q] = pkmax(va[q], vb[q]);
      mn[q] = pkmin(va[q], vb[q]);
    }
    // --- sums: per-col pair (va_j, vb_j) via v_perm, then dot2 ---
#pragma unroll
    for (int q = 0; q < 4; ++q) {
      u32 plo = __builtin_amdgcn_perm(va[q], vb[q], 0x01000504u); // col 2q
      u32 phi = __builtin_amdgcn_perm(va[q], vb[q], 0x03020706u); // col 2q+1
      float Slo = halves_sum(plo, 0.f);
      float Shi = halves_sum(phi, 0.f);
      sq[2 * q]     = halves_sq(plo, sq[2 * q]);
      sq[2 * q + 1] = halves_sq(phi, sq[2 * q + 1]);
      sh[2 * q]     += Slo;
      sh[2 * q + 1] += Shi;
      nxS[2 * q]     = fmaf(nx, Slo, nxS[2 * q]);
      nxS[2 * q + 1] = fmaf(nx, Shi, nxS[2 * q + 1]);
      nyS[2 * q]     = fmaf(ny, Slo, nyS[2 * q]);
      nyS[2 * q + 1] = fmaf(ny, Shi, nyS[2 * q + 1]);
      nzS[2 * q]     = fmaf(nz, Slo, nzS[2 * q]);
      nzS[2 * q + 1] = fmaf(nz, Shi, nzS[2 * q + 1]);
    }
    // --- cross-lane reduce of packed max/min over row-lanes (bits 3..5) ---
#pragma unroll
    for (int s = 8; s < 64; s <<= 1) {
#pragma unroll
      for (int q = 0; q < 4; ++q) {
        mx[q] = pkmax(mx[q], __shfl_xor(mx[q], s, 64));
        mn[q] = pkmin(mn[q], __shfl_xor(mn[q], s, 64));
      }
    }
    if (lane < 8) {   // ch == lane; 16B f16 stores, 8 lanes -> 128B/row
      u32x4 wm = {mx[0], mx[1], mx[2], mx[3]};
      *(u32x4*)(gmax + (size_t)iA * 64 + ch * 8) = wm;
      u32x4 wn = {mn[0], mn[1], mn[2], mn[3]};
      *(u32x4*)(gmin + (size_t)iA * 64 + ch * 8) = wn;
    }
    // --- rotate pipeline ---
    va = vaN; vb = vbN; dnxt = d2; iA = iN; iN = i2;
  }

  // --- end-of-kernel reduction of stats partials across row-lanes ---
#pragma unroll
  for (int s = 8; s < 64; s <<= 1) {
#pragma unroll
    for (int j = 0; j < 8; ++j) {
      sh[j]  += __shfl_xor(sh[j], s, 64);
      sq[j]  += __shfl_xor(sq[j], s, 64);
      nxS[j] += __shfl_xor(nxS[j], s, 64);
      nyS[j] += __shfl_xor(nyS[j], s, 64);
      nzS[j] += __shfl_xor(nzS[j], s, 64);
    }
  }
  if (lane < 8) {
#pragma unroll
    for (int j = 0; j < 8; ++j) {
      int col = ch * 8 + j;
      const float* wr = W + col * 67 + 64;
      float w0 = wr[0], w1 = wr[1], w2 = wr[2];
      float sumc = w0 * Lx + w1 * Ly + w2 * Lz;
      float cS   = w0 * nxS[j] + w1 * nyS[j] + w2 * nzS[j];
      float wMw  = w0 * w0 * Mxx + w1 * w1 * Myy + w2 * w2 * Mzz
                 + 2.f * (w0 * w1 * Mxy + w0 * w2 * Mxz + w1 * w2 * Myz);
      stats[(size_t)col * nwaves + wave]        = sh[j] - 16.f * sumc;
      stats[(size_t)(64 + col) * nwaves + wave] = sq[j] - 2.f * cS + 16.f * wMw;
    }
  }
}

// ---------------------------------------------------------------------------
// Kernel 2: reduce per-wave partials -> scale/shift per output column.
// ---------------------------------------------------------------------------
__global__ __launch_bounds__(256) void stats_kernel(
    const float* __restrict__ stats, const float* __restrict__ gamma,
    const float* __restrict__ beta, float* __restrict__ ss, int nwaves) {
  int d = blockIdx.x;    // 0..63
  int t = threadIdx.x;
  const float* r1 = stats + (size_t)d * nwaves;
  const float* r2 = stats + (size_t)(64 + d) * nwaves;
  float a = 0.f, b = 0.f;
  for (int k = t; k < nwaves; k += 256) { a += r1[k]; b += r2[k]; }
  __shared__ float l1[256], l2[256];
  l1[t] = a; l2[t] = b;
  __syncthreads();
  for (int s = 128; s > 0; s >>= 1) {
    if (t < s) { l1[t] += l1[t + s]; l2[t] += l2[t + s]; }
    __syncthreads();
  }
  if (t == 0) {
    const float inv_ne = 1.0f / (float)N_EDGES;
    float mean = l1[0] * inv_ne;
    float var  = fmaxf(l2[0] * inv_ne - mean * mean, 0.f);
    float sc   = gamma[d] * rsqrtf(var + EPS);
    ss[d]      = sc;
    ss[64 + d] = beta[d] - mean * sc;
  }
}

// ---------------------------------------------------------------------------
// Kernel 3: out[i][d] = relu((sel - c_i[d]) * sc[d] + sh[d]);
// sel = gmax if sc>=0 else gmin (relu(affine(.)) monotone per column);
// c_i[d] = Wn[d] . node[i] computed on the fly (cached reads).
// ---------------------------------------------------------------------------
__global__ __launch_bounds__(256) void finalize_kernel(
    const _Float16* __restrict__ gmax, const _Float16* __restrict__ gmin,
    const float* __restrict__ ss, const float* __restrict__ nodep,
    const float* __restrict__ W, float* __restrict__ out) {
  int idx = blockIdx.x * 256 + threadIdx.x;   // < 6,400,000
  int d = idx & 63;
  int i = idx >> 6;
  float sc = ss[d], sh = ss[64 + d];
  const _Float16* sel = (sc >= 0.f) ? gmax : gmin;
  float v = (float)sel[idx];
  float nx = nodep[3 * i], ny = nodep[3 * i + 1], nz = nodep[3 * i + 2];
  const float* wr = W + d * 67 + 64;
  float c = fmaf(wr[2], nz, fmaf(wr[1], ny, wr[0] * nx));
  out[idx] = fmaxf(fmaf(v - c, sc, sh), 0.f);
}

// ---------------------------------------------------------------------------
extern "C" void kernel_launch(void* const* d_in, const int* in_sizes, int n_in,
                              void* d_out, int out_size, void* d_ws, size_t ws_size,
                              hipStream_t stream) {
  const float* nodep = (const float*)d_in[0];
  const float* feat  = (const float*)d_in[1];
  const float* W     = (const float*)d_in[2];
  const float* gamma = (const float*)d_in[3];
  const float* beta  = (const float*)d_in[4];
  const int*   edges = (const int*)d_in[5];

  // workspace layout (all 16B-aligned; total 42,594,816 B <= proven bound)
  char* ws = (char*)d_ws;
  unsigned short* g = (unsigned short*)ws;                    // 12,800,000 B
  _Float16* gmax = (_Float16*)(ws + 12800000);                // 12,800,000 B
  _Float16* gmin = (_Float16*)(ws + 25600000);                // 12,800,000 B
  float* stats = (float*)(ws + 38400000);                     //  4,194,304 B
  float* ss    = (float*)(ws + 38400000 + 4194304);           //       512 B
  float* out   = (float*)d_out;

  const int nwaves = 8192;   // 2048 blocks x 4 waves; ~12.2 nodes per wave

  gemm_kernel<<<1563, 256, 0, stream>>>(nodep, feat, W, g);
  gather_kernel<<<2048, 256, 0, stream>>>(nodep, edges, (const _Float16*)g, W,
                                          gmax, gmin, stats, nwaves);
  stats_kernel<<<64, 256, 0, stream>>>(stats, gamma, beta, ss, nwaves);
  finalize_kernel<<<25000, 256, 0, stream>>>(gmax, gmin, ss, nodep, W, out);
}